// Round 2
// baseline (410.301 us; speedup 1.0000x reference)
//
#include <hip/hip_runtime.h>

// ReconstructionLoss: loss = mean(|masks - onehot(argmax_c(src_stft[:,:,:F,:]))|)
// masks [16,512,1024,4] f32, src_stft [16,512,2048,4] f32, out = scalar f32.
// HBM-bound: 256 MiB read -> ~43 us ideal at 6.3 TB/s.
// Structure: fully-unrolled 8 groups/thread, all 16 dwordx4 loads in flight
// before consumption (MLP), then wave/block reduce + 1 atomic per block.

#define F_SHIFT 10
#define F_MASK  1023
#define GROUPS_PER_THREAD 8

__global__ __launch_bounds__(256) void recon_loss_kernel(
    const float4* __restrict__ masks,   // G groups of 4 floats
    const float4* __restrict__ src,     // per (b,t): 1024 gt groups then 1024 phase groups
    float* __restrict__ out, float inv_n)
{
    const unsigned int tid    = blockIdx.x * blockDim.x + threadIdx.x;
    const unsigned int stride = gridDim.x * blockDim.x;   // 1,048,576

    float4 gv[GROUPS_PER_THREAD];
    float4 mv[GROUPS_PER_THREAD];

    // Issue all loads first — grid-strided so each wave's 64 lanes stay
    // contiguous (perfectly coalesced 1 KiB per instruction).
    #pragma unroll
    for (int i = 0; i < GROUPS_PER_THREAD; ++i) {
        unsigned int g  = tid + (unsigned int)i * stride;
        unsigned int bt = g >> F_SHIFT;
        unsigned int f  = g & F_MASK;
        gv[i] = src[(bt << (F_SHIFT + 1)) | f];  // magnitude half of slab bt
        mv[i] = masks[g];
    }

    float acc = 0.0f;
    #pragma unroll
    for (int i = 0; i < GROUPS_PER_THREAD; ++i) {
        float4 gt = gv[i];
        float4 m  = mv[i];
        // first-max argmax over C=4 (strict > keeps first max, like jnp/torch)
        int   idx  = 0;
        float best = gt.x;
        if (gt.y > best) { best = gt.y; idx = 1; }
        if (gt.z > best) { best = gt.z; idx = 2; }
        if (gt.w > best) { best = gt.w; idx = 3; }
        acc += fabsf(m.x - (idx == 0 ? 1.0f : 0.0f));
        acc += fabsf(m.y - (idx == 1 ? 1.0f : 0.0f));
        acc += fabsf(m.z - (idx == 2 ? 1.0f : 0.0f));
        acc += fabsf(m.w - (idx == 3 ? 1.0f : 0.0f));
    }

    // wave-64 butterfly reduce
    #pragma unroll
    for (int off = 32; off > 0; off >>= 1)
        acc += __shfl_down(acc, off, 64);

    __shared__ float wave_sums[4];
    int lane = threadIdx.x & 63;
    int wave = threadIdx.x >> 6;
    if (lane == 0) wave_sums[wave] = acc;
    __syncthreads();

    if (threadIdx.x == 0) {
        float blk = wave_sums[0] + wave_sums[1] + wave_sums[2] + wave_sums[3];
        atomicAdd(out, blk * inv_n);   // pre-scaled mean
    }
}

extern "C" void kernel_launch(void* const* d_in, const int* in_sizes, int n_in,
                              void* d_out, int out_size, void* d_ws, size_t ws_size,
                              hipStream_t stream) {
    const float4* masks = (const float4*)d_in[0];
    const float4* src   = (const float4*)d_in[1];
    float* out = (float*)d_out;

    const unsigned int n_mask_elems = (unsigned int)in_sizes[0];   // 33,554,432
    const float inv_n = 1.0f / (float)n_mask_elems;

    // Harness re-poisons d_out to 0xAA before every timed replay: zero it here.
    hipMemsetAsync(d_out, 0, sizeof(float), stream);

    // 4096 blocks x 256 threads x 8 groups/thread == 8,388,608 groups exactly.
    recon_loss_kernel<<<4096, 256, 0, stream>>>(masks, src, out, inv_n);
}